// Round 2
// baseline (4296.697 us; speedup 1.0000x reference)
//
#include <hip/hip_runtime.h>
#include <hip/hip_bf16.h>
#include <stdint.h>

// TiedEmbeddingLinear: out[8192, 32768] = x[8192,4096] . W^T
// Two-pass: (1) dequant NF4 W -> bf16 in ws, (2) convert x -> bf16 in ws,
// (3) bf16 NT-GEMM (m97 structure: global_load_lds width-16, 128x128 tile),
// absmax applied in GEMM epilogue. Fallback to fused kernel if ws too small.

#define M_DIM 8192
#define N_DIM 32768
#define K_DIM 4096
#define P_DIM 2048

typedef __attribute__((ext_vector_type(8))) short short8;
typedef __attribute__((ext_vector_type(4))) float f32x4;

__device__ __forceinline__ ushort f2bf(float f) {
    union { __hip_bfloat16 b; ushort u; } cv;
    cv.b = __float2bfloat16(f);
    return cv.u;
}

__device__ __forceinline__ void gload16(const ushort* g, ushort* l) {
    __builtin_amdgcn_global_load_lds(
        (const __attribute__((address_space(1))) unsigned int*)g,
        (__attribute__((address_space(3))) unsigned int*)l,
        16, 0, 0);
}

// ---------------- pass 1: dequant W (67.1M ints -> 134.2M bf16) ----------------
__global__ __launch_bounds__(256) void dequant_w(
    const int* __restrict__ qw, const float* __restrict__ cb,
    uint32_t* __restrict__ wout)
{
    __shared__ uint32_t lut[256];
    const int tid = threadIdx.x;
    {
        const uint32_t h = f2bf(cb[(tid >> 4) & 15]);   // high nibble -> even d
        const uint32_t l = f2bf(cb[tid & 15]);          // low nibble  -> odd d
        lut[tid] = h | (l << 16);                       // little-endian: even d first
    }
    __syncthreads();

    const size_t base = (size_t)blockIdx.x * 256 + tid;
    const int4* q4 = (const int4*)qw;
    uint4* w4 = (uint4*)wout;
    #pragma unroll
    for (int it = 0; it < 16; ++it) {
        const size_t idx = base + (size_t)it * (4096 * 256);
        const int4 q = q4[idx];
        uint4 w;
        w.x = lut[q.x & 255]; w.y = lut[q.y & 255];
        w.z = lut[q.z & 255]; w.w = lut[q.w & 255];
        w4[idx] = w;
    }
}

// ---------------- pass 2: x fp32 -> bf16 ----------------
__global__ __launch_bounds__(256) void conv_x(
    const float* __restrict__ x, ushort* __restrict__ xb)
{
    const size_t base = (size_t)blockIdx.x * 256 + threadIdx.x;
    #pragma unroll
    for (int it = 0; it < 8; ++it) {
        const size_t idx = (base + (size_t)it * (2048 * 256)) * 8;
        const float4 a = *(const float4*)(x + idx);
        const float4 b = *(const float4*)(x + idx + 4);
        short8 o;
        o[0] = f2bf(a.x); o[1] = f2bf(a.y); o[2] = f2bf(a.z); o[3] = f2bf(a.w);
        o[4] = f2bf(b.x); o[5] = f2bf(b.y); o[6] = f2bf(b.z); o[7] = f2bf(b.w);
        *(short8*)(xb + idx) = o;
    }
}

// ---------------- pass 3: bf16 NT-GEMM, m97 structure ----------------
// A = xb [M,K] row-major, B = wb [N,K] row-major, out[M,N] fp32 * absmax[col]
__global__ __launch_bounds__(256) void gemm_bt(
    const ushort* __restrict__ xb, const ushort* __restrict__ wb,
    const float* __restrict__ absmax, float* __restrict__ out)
{
    __shared__ ushort As[128 * 64];   // 16 KB, linear (global_load_lds needs linear)
    __shared__ ushort Bs[128 * 64];   // 16 KB

    // bijective XCD swizzle: nwg = 16384, 16384 % 8 == 0
    const int bid = blockIdx.x;
    const int wg = (bid & 7) * 2048 + (bid >> 3);
    const int gm0 = (wg & 63) << 7;   // m fast: 64 consecutive blocks share W panel
    const int gn0 = (wg >> 6) << 7;

    const int tid = threadIdx.x;
    const int lane = tid & 63;
    const int wv = tid >> 6;
    const int wr = wv >> 1, wc = wv & 1;
    const int lr = lane & 15, g = lane >> 4;

    f32x4 acc[4][4] = {};

    // staging: wave wv op i covers LDS rows r0 = wv*32+i*8 .. +7 (1 KiB chunk)
    // lane l -> row r0 + (l>>3), col bf16 (l&7)*8  (matches lds base + lane*16B)
    const int srow = lane >> 3;
    const int scol = (lane & 7) * 8;

    const ushort* xsrc = xb + (size_t)gm0 * K_DIM + scol;
    const ushort* wsrc = wb + (size_t)gn0 * K_DIM + scol;

    for (int kt = 0; kt < K_DIM / 64; ++kt) {
        const ushort* xk = xsrc + kt * 64;
        const ushort* wk = wsrc + kt * 64;
        #pragma unroll
        for (int i = 0; i < 4; ++i) {
            const int r0 = wv * 32 + i * 8;
            gload16(xk + (size_t)(r0 + srow) * K_DIM, &As[r0 * 64]);
        }
        #pragma unroll
        for (int i = 0; i < 4; ++i) {
            const int r0 = wv * 32 + i * 8;
            gload16(wk + (size_t)(r0 + srow) * K_DIM, &Bs[r0 * 64]);
        }
        __syncthreads();   // compiler drains vmcnt before s_barrier -> LDS ready

        #pragma unroll
        for (int kk = 0; kk < 64; kk += 32) {
            short8 af[4], bf[4];
            #pragma unroll
            for (int m = 0; m < 4; ++m)
                af[m] = *(const short8*)(&As[(wr * 64 + m * 16 + lr) * 64 + kk + g * 8]);
            #pragma unroll
            for (int n = 0; n < 4; ++n)
                bf[n] = *(const short8*)(&Bs[(wc * 64 + n * 16 + lr) * 64 + kk + g * 8]);
            #pragma unroll
            for (int m = 0; m < 4; ++m)
                #pragma unroll
                for (int n = 0; n < 4; ++n)
                    acc[m][n] = __builtin_amdgcn_mfma_f32_16x16x32_bf16(af[m], bf[n], acc[m][n], 0, 0, 0);
        }
        __syncthreads();
    }

    // epilogue: scale by absmax[col], store fp32
    float am[4];
    #pragma unroll
    for (int n = 0; n < 4; ++n)
        am[n] = absmax[gn0 + wc * 64 + n * 16 + lr];

    #pragma unroll
    for (int m = 0; m < 4; ++m) {
        const int row = gm0 + wr * 64 + m * 16 + g * 4;
        #pragma unroll
        for (int n = 0; n < 4; ++n) {
            const int col = gn0 + wc * 64 + n * 16 + lr;
            #pragma unroll
            for (int r = 0; r < 4; ++r)
                out[(size_t)(row + r) * N_DIM + col] = acc[m][n][r] * am[n];
        }
    }
}

// ---------------- fallback: round-1 fused kernel ----------------
#define LDS_STRIDE 72
__global__ __launch_bounds__(256) void nf4_gemm(
    const float* __restrict__ x, const int* __restrict__ qw,
    const float* __restrict__ absmax, const float* __restrict__ cb,
    float* __restrict__ out)
{
    __shared__ ushort As[128 * LDS_STRIDE];
    __shared__ ushort Bs[128 * LDS_STRIDE];
    __shared__ uint32_t lut[256];

    const int tid = threadIdx.x;
    const int gm0 = blockIdx.x * 128;
    const int gn0 = blockIdx.y * 128;
    {
        const uint32_t h = f2bf(cb[(tid >> 4) & 15]);
        const uint32_t l = f2bf(cb[tid & 15]);
        lut[tid] = h | (l << 16);
    }
    __syncthreads();

    const int lane = tid & 63;
    const int wv = tid >> 6;
    const int wr = wv >> 1, wc = wv & 1;
    const int lr = lane & 15, g = lane >> 4;

    f32x4 acc[4][4] = {};
    const int ac = tid & 15;
    const int ar = tid >> 4;
    const int bn = tid >> 1;
    const int bh = tid & 1;
    const float* xg = x + (size_t)gm0 * K_DIM + ac * 4;
    const int* qg = qw + (size_t)(gn0 + bn) * P_DIM + bh * 16;

    for (int kt = 0; kt < K_DIM / 64; ++kt) {
        {
            const float* xk = xg + kt * 64;
            #pragma unroll
            for (int p = 0; p < 8; ++p) {
                const int row = ar + p * 16;
                const float4 v = *(const float4*)(xk + (size_t)row * K_DIM);
                ushort4 w4;
                w4.x = f2bf(v.x); w4.y = f2bf(v.y);
                w4.z = f2bf(v.z); w4.w = f2bf(v.w);
                *(ushort4*)(&As[row * LDS_STRIDE + ac * 4]) = w4;
            }
        }
        {
            const int* qk = qg + kt * 32;
            const int4 q0 = *(const int4*)(qk + 0);
            const int4 q1 = *(const int4*)(qk + 4);
            const int4 q2 = *(const int4*)(qk + 8);
            const int4 q3 = *(const int4*)(qk + 12);
            uint4 w0, w1, w2, w3;
            w0.x = lut[q0.x & 255]; w0.y = lut[q0.y & 255];
            w0.z = lut[q0.z & 255]; w0.w = lut[q0.w & 255];
            w1.x = lut[q1.x & 255]; w1.y = lut[q1.y & 255];
            w1.z = lut[q1.z & 255]; w1.w = lut[q1.w & 255];
            w2.x = lut[q2.x & 255]; w2.y = lut[q2.y & 255];
            w2.z = lut[q2.z & 255]; w2.w = lut[q2.w & 255];
            w3.x = lut[q3.x & 255]; w3.y = lut[q3.y & 255];
            w3.z = lut[q3.z & 255]; w3.w = lut[q3.w & 255];
            uint32_t* bp = (uint32_t*)(&Bs[bn * LDS_STRIDE + bh * 32]);
            *(uint4*)(bp + 0)  = w0;
            *(uint4*)(bp + 4)  = w1;
            *(uint4*)(bp + 8)  = w2;
            *(uint4*)(bp + 12) = w3;
        }
        __syncthreads();
        #pragma unroll
        for (int kk = 0; kk < 64; kk += 32) {
            short8 af[4], bf[4];
            #pragma unroll
            for (int m = 0; m < 4; ++m)
                af[m] = *(const short8*)(&As[(wr * 64 + m * 16 + lr) * LDS_STRIDE + kk + g * 8]);
            #pragma unroll
            for (int n = 0; n < 4; ++n)
                bf[n] = *(const short8*)(&Bs[(wc * 64 + n * 16 + lr) * LDS_STRIDE + kk + g * 8]);
            #pragma unroll
            for (int m = 0; m < 4; ++m)
                #pragma unroll
                for (int n = 0; n < 4; ++n)
                    acc[m][n] = __builtin_amdgcn_mfma_f32_16x16x32_bf16(af[m], bf[n], acc[m][n], 0, 0, 0);
        }
        __syncthreads();
    }

    float am[4];
    #pragma unroll
    for (int n = 0; n < 4; ++n)
        am[n] = absmax[gn0 + wc * 64 + n * 16 + lr];
    #pragma unroll
    for (int m = 0; m < 4; ++m) {
        const int row = gm0 + wr * 64 + m * 16 + g * 4;
        #pragma unroll
        for (int n = 0; n < 4; ++n) {
            const int col = gn0 + wc * 64 + n * 16 + lr;
            #pragma unroll
            for (int r = 0; r < 4; ++r)
                out[(size_t)(row + r) * N_DIM + col] = acc[m][n][r] * am[n];
        }
    }
}

extern "C" void kernel_launch(void* const* d_in, const int* in_sizes, int n_in,
                              void* d_out, int out_size, void* d_ws, size_t ws_size,
                              hipStream_t stream) {
    const float* x      = (const float*)d_in[0];
    const int*   qw     = (const int*)d_in[1];
    const float* absmax = (const float*)d_in[2];
    const float* cb     = (const float*)d_in[3];
    float* out = (float*)d_out;

    const size_t W_BYTES = (size_t)N_DIM * K_DIM * 2;   // 256 MiB bf16 W
    const size_t X_BYTES = (size_t)M_DIM * K_DIM * 2;   // 64 MiB bf16 x

    if (ws_size >= W_BYTES + X_BYTES) {
        uint32_t* wq = (uint32_t*)d_ws;
        ushort* xbf = (ushort*)((char*)d_ws + W_BYTES);
        dequant_w<<<4096, 256, 0, stream>>>(qw, cb, wq);
        conv_x<<<2048, 256, 0, stream>>>(x, xbf);
        gemm_bt<<<16384, 256, 0, stream>>>(xbf, (const ushort*)wq, absmax, out);
    } else {
        // fallback: fused single-pass (round-1 kernel)
        nf4_gemm<<<dim3(M_DIM / 128, N_DIM / 128), 256, 0, stream>>>(x, qw, absmax, cb, out);
    }
}

// Round 3
// 2617.793 us; speedup vs baseline: 1.6413x; 1.6413x over previous
//
#include <hip/hip_runtime.h>
#include <hip/hip_bf16.h>
#include <stdint.h>

// TiedEmbeddingLinear: out[8192, 32768] = x[8192,4096] . W^T
// Pass 1: dequant NF4 W -> bf16 (ws). Pass 2: x fp32 -> bf16 (ws).
// Pass 3: 256x256-tile 8-phase bf16 NT-GEMM (counted vmcnt, granule-XOR LDS
// swizzle, setprio), absmax folded into epilogue.

#define M_DIM 8192
#define N_DIM 32768
#define K_DIM 4096
#define NT    64        // K / BK, BK = 64

typedef __attribute__((ext_vector_type(8))) short short8;
typedef __attribute__((ext_vector_type(4))) float f32x4;

__device__ __forceinline__ ushort f2bf(float f) {
    union { __hip_bfloat16 b; ushort u; } cv;
    cv.b = __float2bfloat16(f);
    return cv.u;
}

__device__ __forceinline__ void gload16(const ushort* g, ushort* l) {
    __builtin_amdgcn_global_load_lds(
        (const __attribute__((address_space(1))) unsigned int*)g,
        (__attribute__((address_space(3))) unsigned int*)l,
        16, 0, 0);
}

#define BAR()    asm volatile("s_barrier" ::: "memory")
#define VMCNT4() asm volatile("s_waitcnt vmcnt(4)" ::: "memory")

// ---------------- pass 1: dequant W ----------------
__global__ __launch_bounds__(256) void dequant_w(
    const int* __restrict__ qw, const float* __restrict__ cb,
    uint32_t* __restrict__ wout)
{
    __shared__ uint32_t lut[256];
    const int tid = threadIdx.x;
    {
        const uint32_t h = f2bf(cb[(tid >> 4) & 15]);   // high nibble -> even d
        const uint32_t l = f2bf(cb[tid & 15]);          // low nibble  -> odd d
        lut[tid] = h | (l << 16);
    }
    __syncthreads();

    const size_t base = (size_t)blockIdx.x * 256 + tid;
    const int4* q4 = (const int4*)qw;
    uint4* w4 = (uint4*)wout;
    #pragma unroll
    for (int it = 0; it < 16; ++it) {
        const size_t idx = base + (size_t)it * (4096 * 256);
        const int4 q = q4[idx];
        uint4 w;
        w.x = lut[q.x & 255]; w.y = lut[q.y & 255];
        w.z = lut[q.z & 255]; w.w = lut[q.w & 255];
        w4[idx] = w;
    }
}

// ---------------- pass 2: x fp32 -> bf16 ----------------
__global__ __launch_bounds__(256) void conv_x(
    const float* __restrict__ x, ushort* __restrict__ xb)
{
    const size_t base = (size_t)blockIdx.x * 256 + threadIdx.x;
    #pragma unroll
    for (int it = 0; it < 8; ++it) {
        const size_t idx = (base + (size_t)it * (2048 * 256)) * 8;
        const float4 a = *(const float4*)(x + idx);
        const float4 b = *(const float4*)(x + idx + 4);
        short8 o;
        o[0] = f2bf(a.x); o[1] = f2bf(a.y); o[2] = f2bf(a.z); o[3] = f2bf(a.w);
        o[4] = f2bf(b.x); o[5] = f2bf(b.y); o[6] = f2bf(b.z); o[7] = f2bf(b.w);
        *(short8*)(xb + idx) = o;
    }
}

// ---------------- pass 3: 256^2 8-phase bf16 NT-GEMM ----------------
// A = xb [M,K], B = wb [N,K], out[M,N] fp32 scaled by absmax[col].
// 512 thr = 8 waves (2M x 4N); wave out 128x64; BK=64; LDS 128 KiB:
// smA/smB = [buf(2)][half(2)][128 rows x 64 bf16]. Granule XOR swizzle
// (gran ^= row&7) applied on gload SOURCE and on ds_read (both-sides, rule 21).
__global__ __launch_bounds__(512, 2) void gemm_8ph(
    const ushort* __restrict__ xb, const ushort* __restrict__ wb,
    const float* __restrict__ absmax, float* __restrict__ out)
{
    __shared__ ushort smA[32768];   // 64 KiB: (buf*2+half)*8192
    __shared__ ushort smB[32768];   // 64 KiB

    const int tid  = threadIdx.x;
    const int lane = tid & 63;
    const int wv   = tid >> 6;      // 0..7
    const int wm   = wv >> 2;       // 0..1  (A half / output row block)
    const int wn   = wv & 3;        // 0..3  (output col block)

    const int bid = blockIdx.x;
    const int gm0 = (bid & 31) << 8;    // 32 m-tiles fast: concurrent blocks share B panels, A L3-resident
    const int gn0 = (bid >> 5) << 8;

    // staging decomposition: wave covers rows wv*16 .. +15 of each 128-row half
    const int l8    = lane >> 3;             // 0..7 (row within 8-row chunk)
    const int sgran = (lane & 7) ^ l8;       // swizzled SOURCE granule (16B units)

    const ushort* aSrc = xb + (size_t)(gm0 + wv * 16 + l8) * K_DIM + sgran * 8;
    const ushort* bSrc = wb + (size_t)(gn0 + wv * 16 + l8) * K_DIM + sgran * 8;

    // fragment read decomposition
    const int lr  = lane & 15;
    const int g   = lane >> 4;
    const int lr7 = lane & 7;
    const int brow0 = (wn & 1) * 64;         // row offset within wave's B half

    f32x4  acc[8][4] = {};
    short8 af[4][2], bf[4][2];

    // swizzled fragment read: row*64 ushorts/row; granule (s*4+g) XOR (row&7 == lr7)
    #define LDFRAG(P, ROW, S) \
        (*(const short8*)((P) + ((ROW) + lr) * 64 + ((((S) * 4 + g) ^ lr7) * 8)))

    #define STAGE_A(TB, H, KT) do { \
        ushort* _d = smA + ((TB) * 2 + (H)) * 8192 + wv * 1024; \
        gload16(aSrc + (size_t)((H) * 128 + 0) * K_DIM + (KT) * 64, _d); \
        gload16(aSrc + (size_t)((H) * 128 + 8) * K_DIM + (KT) * 64, _d + 512); \
    } while (0)
    #define STAGE_B(TB, H, KT) do { \
        ushort* _d = smB + ((TB) * 2 + (H)) * 8192 + wv * 1024; \
        gload16(bSrc + (size_t)((H) * 128 + 0) * K_DIM + (KT) * 64, _d); \
        gload16(bSrc + (size_t)((H) * 128 + 8) * K_DIM + (KT) * 64, _d + 512); \
    } while (0)

    #define MFMAS(MB, NB) do { \
        __builtin_amdgcn_s_setprio(1); \
        _Pragma("unroll") \
        for (int m = 0; m < 4; ++m) \
            _Pragma("unroll") \
            for (int n = 0; n < 2; ++n) \
                _Pragma("unroll") \
                for (int s = 0; s < 2; ++s) \
                    acc[(MB) + m][(NB) + n] = __builtin_amdgcn_mfma_f32_16x16x32_bf16( \
                        af[m][s], bf[(NB) + n][s], acc[(MB) + m][(NB) + n], 0, 0, 0); \
        __builtin_amdgcn_s_setprio(0); \
    } while (0)

    // ---- prologue: stage A(0),B(0) -> buf0; B(1) -> buf1; retire first 8 ----
    STAGE_A(0, 0, 0); STAGE_A(0, 1, 0);
    STAGE_B(0, 0, 0); STAGE_B(0, 1, 0);
    STAGE_B(1, 0, 1); STAGE_B(1, 1, 1);
    VMCNT4();           // A(0),B(0) landed; B(1)'s 4 loads stay in flight
    BAR();

    for (int j = 0; j < NT; ++j) {
        const int buf = j & 1;
        const ushort* Ar = smA + (buf * 2 + wm) * 8192;
        const ushort* Br = smB + (buf * 2 + (wn >> 1)) * 8192;

        // ---- P1: read A m0-3 + B n0-1; stage A-half0(j+1) into buf^1 ----
        #pragma unroll
        for (int m = 0; m < 4; ++m) {
            af[m][0] = LDFRAG(Ar, m * 16, 0);
            af[m][1] = LDFRAG(Ar, m * 16, 1);
        }
        #pragma unroll
        for (int n = 0; n < 2; ++n) {
            bf[n][0] = LDFRAG(Br, brow0 + n * 16, 0);
            bf[n][1] = LDFRAG(Br, brow0 + n * 16, 1);
        }
        if (j + 1 < NT) STAGE_A(buf ^ 1, 0, j + 1);
        BAR();
        MFMAS(0, 0);
        BAR();

        // ---- P2: read B n2-3; stage A-half1(j+1) ----
        #pragma unroll
        for (int n = 2; n < 4; ++n) {
            bf[n][0] = LDFRAG(Br, brow0 + n * 16, 0);
            bf[n][1] = LDFRAG(Br, brow0 + n * 16, 1);
        }
        if (j + 1 < NT) STAGE_A(buf ^ 1, 1, j + 1);
        BAR();
        MFMAS(0, 2);
        BAR();

        // ---- P3: read A m4-7; stage B-half0(j+2) into buf (B(j) dead after P2) ----
        #pragma unroll
        for (int m = 0; m < 4; ++m) {
            af[m][0] = LDFRAG(Ar, (4 + m) * 16, 0);
            af[m][1] = LDFRAG(Ar, (4 + m) * 16, 1);
        }
        if (j + 2 < NT) STAGE_B(buf, 0, j + 2);
        BAR();
        MFMAS(4, 2);
        BAR();

        // ---- P4: stage B-half1(j+2); counted vmcnt (retire A(j+1),B(j+1)) ----
        if (j + 2 < NT) STAGE_B(buf, 1, j + 2);
        BAR();
        MFMAS(4, 0);
        VMCNT4();
        BAR();
    }

    // ---- epilogue: absmax[col] scale, fp32 store ----
    float am[4];
    #pragma unroll
    for (int n = 0; n < 4; ++n)
        am[n] = absmax[gn0 + wn * 64 + n * 16 + lr];

    const int row0 = gm0 + wm * 128 + g * 4;
    const int col0 = gn0 + wn * 64 + lr;
    #pragma unroll
    for (int m = 0; m < 8; ++m) {
        #pragma unroll
        for (int n = 0; n < 4; ++n) {
            #pragma unroll
            for (int r = 0; r < 4; ++r) {
                out[(size_t)(row0 + m * 16 + r) * N_DIM + col0 + n * 16] =
                    acc[m][n][r] * am[n];
            }
        }
    }
}

extern "C" void kernel_launch(void* const* d_in, const int* in_sizes, int n_in,
                              void* d_out, int out_size, void* d_ws, size_t ws_size,
                              hipStream_t stream) {
    const float* x      = (const float*)d_in[0];
    const int*   qw     = (const int*)d_in[1];
    const float* absmax = (const float*)d_in[2];
    const float* cb     = (const float*)d_in[3];
    float* out = (float*)d_out;

    const size_t W_BYTES = (size_t)N_DIM * K_DIM * 2;   // 256 MiB bf16 W
    uint32_t* wq  = (uint32_t*)d_ws;
    ushort*   xbf = (ushort*)((char*)d_ws + W_BYTES);

    dequant_w<<<4096, 256, 0, stream>>>(qw, cb, wq);
    conv_x<<<2048, 256, 0, stream>>>(x, xbf);
    gemm_8ph<<<dim3((M_DIM / 256) * (N_DIM / 256)), dim3(512), 0, stream>>>(
        xbf, (const ushort*)wq, absmax, out);
}

// Round 5
// 1995.378 us; speedup vs baseline: 2.1533x; 1.3119x over previous
//
#include <hip/hip_runtime.h>
#include <hip/hip_bf16.h>
#include <stdint.h>

// TiedEmbeddingLinear: out[8192, 32768] = x[8192,4096] . W^T
// Pass 1: dequant NF4 W -> bf16 (ws). Pass 2: x fp32 -> bf16 (ws).
// Pass 3: 256x256 8-phase bf16 NT-GEMM, asm ds_read_b128 + counted vmcnt.
// R5 fix: tail-aware vmcnt — at j+2>=NT there is no next-B in flight, so
// vmcnt(4) must become vmcnt(0) or the last K-tile's A is read while its
// staging writes are still in flight (R4's corruption).

#define M_DIM 8192
#define N_DIM 32768
#define K_DIM 4096
#define NT    64        // K / BK, BK = 64

typedef __attribute__((ext_vector_type(8))) short short8;
typedef __attribute__((ext_vector_type(4))) float f32x4;

__device__ __forceinline__ ushort f2bf(float f) {
    union { __hip_bfloat16 b; ushort u; } cv;
    cv.b = __float2bfloat16(f);
    return cv.u;
}

__device__ __forceinline__ void gload16(const ushort* g, ushort* l) {
    __builtin_amdgcn_global_load_lds(
        (const __attribute__((address_space(1))) unsigned int*)g,
        (__attribute__((address_space(3))) unsigned int*)l,
        16, 0, 0);
}

// inline-asm LDS read: opaque to alias analysis -> no compiler vmcnt drains.
__device__ __forceinline__ short8 ldsread128(const ushort* p) {
    short8 r;
    uint32_t a = (uint32_t)(uintptr_t)(const __attribute__((address_space(3))) ushort*)p;
    asm volatile("ds_read_b128 %0, %1" : "=v"(r) : "v"(a));
    return r;
}

#define BAR()    asm volatile("s_barrier" ::: "memory")
#define VMCNT4() asm volatile("s_waitcnt vmcnt(4)" ::: "memory")
#define VMCNT0() asm volatile("s_waitcnt vmcnt(0)" ::: "memory")
#define LGKM0()  do { asm volatile("s_waitcnt lgkmcnt(0)" ::: "memory"); \
                      __builtin_amdgcn_sched_barrier(0); } while (0)

// ---------------- pass 1: dequant W ----------------
__global__ __launch_bounds__(256) void dequant_w(
    const int* __restrict__ qw, const float* __restrict__ cb,
    uint32_t* __restrict__ wout)
{
    __shared__ uint32_t lut[256];
    const int tid = threadIdx.x;
    {
        const uint32_t h = f2bf(cb[(tid >> 4) & 15]);   // high nibble -> even d
        const uint32_t l = f2bf(cb[tid & 15]);          // low nibble  -> odd d
        lut[tid] = h | (l << 16);
    }
    __syncthreads();

    const size_t base = (size_t)blockIdx.x * 256 + tid;
    const int4* q4 = (const int4*)qw;
    uint4* w4 = (uint4*)wout;
    #pragma unroll
    for (int it = 0; it < 16; ++it) {
        const size_t idx = base + (size_t)it * (4096 * 256);
        const int4 q = q4[idx];
        uint4 w;
        w.x = lut[q.x & 255]; w.y = lut[q.y & 255];
        w.z = lut[q.z & 255]; w.w = lut[q.w & 255];
        w4[idx] = w;
    }
}

// ---------------- pass 2: x fp32 -> bf16 ----------------
__global__ __launch_bounds__(256) void conv_x(
    const float* __restrict__ x, ushort* __restrict__ xb)
{
    const size_t base = (size_t)blockIdx.x * 256 + threadIdx.x;
    #pragma unroll
    for (int it = 0; it < 8; ++it) {
        const size_t idx = (base + (size_t)it * (2048 * 256)) * 8;
        const float4 a = *(const float4*)(x + idx);
        const float4 b = *(const float4*)(x + idx + 4);
        short8 o;
        o[0] = f2bf(a.x); o[1] = f2bf(a.y); o[2] = f2bf(a.z); o[3] = f2bf(a.w);
        o[4] = f2bf(b.x); o[5] = f2bf(b.y); o[6] = f2bf(b.z); o[7] = f2bf(b.w);
        *(short8*)(xb + idx) = o;
    }
}

// ---------------- pass 3: 256^2 8-phase bf16 NT-GEMM ----------------
__global__ __launch_bounds__(512, 2) void gemm_8ph(
    const ushort* __restrict__ xb, const ushort* __restrict__ wb,
    const float* __restrict__ absmax, float* __restrict__ out)
{
    __shared__ ushort smA[32768];   // 64 KiB: (buf*2+half)*8192
    __shared__ ushort smB[32768];   // 64 KiB

    const int tid  = threadIdx.x;
    const int lane = tid & 63;
    const int wv   = tid >> 6;      // 0..7
    const int wm   = wv >> 2;       // 0..1
    const int wn   = wv & 3;        // 0..3

    const int bid = blockIdx.x;
    const int gm0 = (bid & 31) << 8;    // 32 m-tiles fast: B panels shared, A L3-resident
    const int gn0 = (bid >> 5) << 8;

    const int l8    = lane >> 3;             // row within 8-row chunk
    const int sgran = (lane & 7) ^ l8;       // swizzled SOURCE granule (16B units)

    const ushort* aSrc = xb + (size_t)(gm0 + wv * 16 + l8) * K_DIM + sgran * 8;
    const ushort* bSrc = wb + (size_t)(gn0 + wv * 16 + l8) * K_DIM + sgran * 8;

    const int lr  = lane & 15;
    const int g   = lane >> 4;
    const int lr7 = lane & 7;
    const int brow0 = (wn & 1) * 64;

    f32x4  acc[8][4] = {};
    short8 af[4][2], bf[4][2];

    #define LDFRAG(P, ROW, S) \
        ldsread128((P) + ((ROW) + lr) * 64 + ((((S) * 4 + g) ^ lr7) * 8))

    #define STAGE_A(TB, H, KT) do { \
        ushort* _d = smA + ((TB) * 2 + (H)) * 8192 + wv * 1024; \
        gload16(aSrc + (size_t)((H) * 128 + 0) * K_DIM + (KT) * 64, _d); \
        gload16(aSrc + (size_t)((H) * 128 + 8) * K_DIM + (KT) * 64, _d + 512); \
    } while (0)
    #define STAGE_B(TB, H, KT) do { \
        ushort* _d = smB + ((TB) * 2 + (H)) * 8192 + wv * 1024; \
        gload16(bSrc + (size_t)((H) * 128 + 0) * K_DIM + (KT) * 64, _d); \
        gload16(bSrc + (size_t)((H) * 128 + 8) * K_DIM + (KT) * 64, _d + 512); \
    } while (0)

    #define MFMAS(MB, NB) do { \
        __builtin_amdgcn_s_setprio(1); \
        _Pragma("unroll") \
        for (int m = 0; m < 4; ++m) \
            _Pragma("unroll") \
            for (int n = 0; n < 2; ++n) \
                _Pragma("unroll") \
                for (int s = 0; s < 2; ++s) \
                    acc[(MB) + m][(NB) + n] = __builtin_amdgcn_mfma_f32_16x16x32_bf16( \
                        af[m][s], bf[(NB) + n][s], acc[(MB) + m][(NB) + n], 0, 0, 0); \
        __builtin_amdgcn_s_setprio(0); \
    } while (0)

    // ---- prologue: A(0),B(0) -> buf0; B(1) -> buf1 ----
    STAGE_A(0, 0, 0); STAGE_A(0, 1, 0);
    STAGE_B(0, 0, 0); STAGE_B(0, 1, 0);
    STAGE_B(1, 0, 1); STAGE_B(1, 1, 1);
    VMCNT4();           // A(0),B(0) landed; B(1)'s 4 loads stay in flight
    BAR();

    for (int j = 0; j < NT; ++j) {
        const int buf = j & 1;
        const ushort* Ar = smA + (buf * 2 + wm) * 8192;
        const ushort* Br = smB + (buf * 2 + (wn >> 1)) * 8192;

        // ---- P1: read A m0-3 + B n0-1; stage A-half0(j+1) -> buf^1 ----
        #pragma unroll
        for (int m = 0; m < 4; ++m) {
            af[m][0] = LDFRAG(Ar, m * 16, 0);
            af[m][1] = LDFRAG(Ar, m * 16, 1);
        }
        #pragma unroll
        for (int n = 0; n < 2; ++n) {
            bf[n][0] = LDFRAG(Br, brow0 + n * 16, 0);
            bf[n][1] = LDFRAG(Br, brow0 + n * 16, 1);
        }
        if (j + 1 < NT) STAGE_A(buf ^ 1, 0, j + 1);
        BAR();
        LGKM0();
        MFMAS(0, 0);
        BAR();

        // ---- P2: read B n2-3; stage A-half1(j+1) ----
        #pragma unroll
        for (int n = 2; n < 4; ++n) {
            bf[n][0] = LDFRAG(Br, brow0 + n * 16, 0);
            bf[n][1] = LDFRAG(Br, brow0 + n * 16, 1);
        }
        if (j + 1 < NT) STAGE_A(buf ^ 1, 1, j + 1);
        BAR();
        LGKM0();
        MFMAS(0, 2);
        BAR();

        // ---- P3: read A m4-7; stage B-half0(j+2) -> buf (B(j) dead) ----
        #pragma unroll
        for (int m = 0; m < 4; ++m) {
            af[m][0] = LDFRAG(Ar, (4 + m) * 16, 0);
            af[m][1] = LDFRAG(Ar, (4 + m) * 16, 1);
        }
        if (j + 2 < NT) STAGE_B(buf, 0, j + 2);
        BAR();
        LGKM0();
        MFMAS(4, 2);
        BAR();

        // ---- P4: stage B-half1(j+2); tail-aware counted vmcnt ----
        if (j + 2 < NT) STAGE_B(buf, 1, j + 2);
        BAR();
        MFMAS(4, 0);
        if (j + 2 < NT) {
            VMCNT4();   // leave B(j+2)'s 4 loads in flight; A(j+1),B(j+1) retired
        } else {
            VMCNT0();   // tail: no next-B in flight -> drain so A(j+1) lands (R4 bug)
        }
        BAR();
    }

    // ---- epilogue: absmax[col] scale, nontemporal fp32 store ----
    float am[4];
    #pragma unroll
    for (int n = 0; n < 4; ++n)
        am[n] = absmax[gn0 + wn * 64 + n * 16 + lr];

    const int row0 = gm0 + wm * 128 + g * 4;
    const int col0 = gn0 + wn * 64 + lr;
    #pragma unroll
    for (int m = 0; m < 8; ++m) {
        #pragma unroll
        for (int n = 0; n < 4; ++n) {
            #pragma unroll
            for (int r = 0; r < 4; ++r) {
                __builtin_nontemporal_store(
                    acc[m][n][r] * am[n],
                    &out[(size_t)(row0 + m * 16 + r) * N_DIM + col0 + n * 16]);
            }
        }
    }
}

extern "C" void kernel_launch(void* const* d_in, const int* in_sizes, int n_in,
                              void* d_out, int out_size, void* d_ws, size_t ws_size,
                              hipStream_t stream) {
    const float* x      = (const float*)d_in[0];
    const int*   qw     = (const int*)d_in[1];
    const float* absmax = (const float*)d_in[2];
    const float* cb     = (const float*)d_in[3];
    float* out = (float*)d_out;

    const size_t W_BYTES = (size_t)N_DIM * K_DIM * 2;   // 256 MiB bf16 W
    uint32_t* wq  = (uint32_t*)d_ws;
    ushort*   xbf = (ushort*)((char*)d_ws + W_BYTES);

    dequant_w<<<4096, 256, 0, stream>>>(qw, cb, wq);
    conv_x<<<2048, 256, 0, stream>>>(x, xbf);
    gemm_8ph<<<dim3((M_DIM / 256) * (N_DIM / 256)), dim3(512), 0, stream>>>(
        xbf, (const ushort*)wq, absmax, out);
}